// Round 1
// baseline (272.865 us; speedup 1.0000x reference)
//
#include <hip/hip_runtime.h>

#define N_TOK 8192
#define DIN   1024
#define DOUT  1024
#define NE    8

#define BM 128
#define BN 128
#define BK 64

typedef __attribute__((ext_vector_type(8))) short  short8;
typedef __attribute__((ext_vector_type(4))) float  f32x4;

__device__ __forceinline__ unsigned short f2bf(float f) {
  union { float f; unsigned int u; } v; v.f = f;
  unsigned int u = v.u;
  unsigned int r = (u + 0x7fffu + ((u >> 16) & 1u)) >> 16;
  return (unsigned short)r;
}

__device__ __forceinline__ float dot4(float4 a, float4 b) {
  return a.x*b.x + a.y*b.y + a.z*b.z + a.w*b.w;
}

// ---------------- gates: softmax(x @ gw^T + gb) ----------------
// one wave per token; lane covers 16 columns of the 1024-dim dot.
__global__ __launch_bounds__(256) void gates_kernel(
    const float* __restrict__ x, const float* __restrict__ gw,
    const float* __restrict__ gb, float* __restrict__ gates) {
  const int lane = threadIdx.x & 63;
  const int wave = threadIdx.x >> 6;
  const int n = blockIdx.x * 4 + wave;

  const float4* xr = reinterpret_cast<const float4*>(x + (size_t)n * DIN) + lane * 4;
  float4 xv0 = xr[0], xv1 = xr[1], xv2 = xr[2], xv3 = xr[3];

  float p[NE];
#pragma unroll
  for (int e = 0; e < NE; ++e) {
    const float4* wr = reinterpret_cast<const float4*>(gw + e * DIN) + lane * 4;
    float4 w0 = wr[0], w1 = wr[1], w2 = wr[2], w3 = wr[3];
    p[e] = dot4(xv0, w0) + dot4(xv1, w1) + dot4(xv2, w2) + dot4(xv3, w3);
  }
#pragma unroll
  for (int off = 1; off < 64; off <<= 1) {
#pragma unroll
    for (int e = 0; e < NE; ++e) p[e] += __shfl_xor(p[e], off, 64);
  }
  float mx = -1e30f;
#pragma unroll
  for (int e = 0; e < NE; ++e) { p[e] += gb[e]; mx = fmaxf(mx, p[e]); }
  float s = 0.f;
#pragma unroll
  for (int e = 0; e < NE; ++e) { p[e] = __expf(p[e] - mx); s += p[e]; }
  float inv = 1.0f / s;
  if (lane < NE) gates[(size_t)n * NE + lane] = p[lane] * inv;
}

// ---------------- main fused MoE GEMM ----------------
// C[n,o] = sum_k A'[n,k] B'[o,k] + sum_e g[n,e] b[e,o]
// A'[n, e*1024+i] = g[n,e] * x[n,i]  (built on the fly in LDS staging)
// B'[o, e*1024+i] = W[e,o,i]
__global__ __launch_bounds__(256) void moe_gemm(
    const float* __restrict__ x,      // [N_TOK][DIN]
    const float* __restrict__ w,      // [NE][DOUT][DIN]
    const float* __restrict__ bias,   // [NE][DOUT]
    const float* __restrict__ gates,  // [N_TOK][NE]
    float* __restrict__ out) {        // [N_TOK][DOUT]
  __shared__ __align__(16) unsigned short As[BM][BK];
  __shared__ __align__(16) unsigned short Bs[BN][BK];

  const int tid  = threadIdx.x;
  const int bm   = blockIdx.x;
  const int bn   = blockIdx.y;
  const int lane = tid & 63;
  const int wv   = tid >> 6;      // 4 waves, 2x2
  const int wm   = wv >> 1;
  const int wn   = wv & 1;
  const int lr   = lane & 15;           // fragment row/col
  const int lkb  = (lane >> 4) * 8;     // fragment k base

  // staging: 8 lanes per row, each thread 2 float4 (16B bf16 out)
  const int sr = tid >> 3;        // row base (i*32 + sr)
  const int sc = (tid & 7) * 8;   // col (elements)

  f32x4 acc[4][4];
#pragma unroll
  for (int i = 0; i < 4; ++i)
#pragma unroll
    for (int j = 0; j < 4; ++j) acc[i][j] = (f32x4){0.f, 0.f, 0.f, 0.f};

  float gA[4] = {0.f, 0.f, 0.f, 0.f};

  const int KT = (NE * DIN) / BK;   // 128 k-steps
  for (int kt = 0; kt < KT; ++kt) {
    const int e  = kt >> 4;               // expert (16 k-steps each)
    const int kc = (kt << 6) & (DIN - 1); // k offset within expert

    if ((kt & 15) == 0) {
#pragma unroll
      for (int i = 0; i < 4; ++i)
        gA[i] = gates[(size_t)(bm * BM + i * 32 + sr) * NE + e];
    }

    // ---- stage A (gate-scaled x -> bf16) ----
#pragma unroll
    for (int i = 0; i < 4; ++i) {
      const int r = i * 32 + sr;
      const float* src = x + (size_t)(bm * BM + r) * DIN + kc + sc;
      float4 a0 = *reinterpret_cast<const float4*>(src);
      float4 a1 = *reinterpret_cast<const float4*>(src + 4);
      const float g = gA[i];
      short8 v;
      v[0] = (short)f2bf(a0.x * g); v[1] = (short)f2bf(a0.y * g);
      v[2] = (short)f2bf(a0.z * g); v[3] = (short)f2bf(a0.w * g);
      v[4] = (short)f2bf(a1.x * g); v[5] = (short)f2bf(a1.y * g);
      v[6] = (short)f2bf(a1.z * g); v[7] = (short)f2bf(a1.w * g);
      *reinterpret_cast<short8*>(&As[r][sc]) = v;
    }
    // ---- stage B (W -> bf16) ----
#pragma unroll
    for (int i = 0; i < 4; ++i) {
      const int r = i * 32 + sr;
      const float* src = w + ((size_t)e * DOUT + bn * BN + r) * DIN + kc + sc;
      float4 a0 = *reinterpret_cast<const float4*>(src);
      float4 a1 = *reinterpret_cast<const float4*>(src + 4);
      short8 v;
      v[0] = (short)f2bf(a0.x); v[1] = (short)f2bf(a0.y);
      v[2] = (short)f2bf(a0.z); v[3] = (short)f2bf(a0.w);
      v[4] = (short)f2bf(a1.x); v[5] = (short)f2bf(a1.y);
      v[6] = (short)f2bf(a1.z); v[7] = (short)f2bf(a1.w);
      *reinterpret_cast<short8*>(&Bs[r][sc]) = v;
    }
    __syncthreads();

    // ---- compute: 2 k-halves x 4x4 fragments ----
#pragma unroll
    for (int kh = 0; kh < 2; ++kh) {
      short8 af[4], bfr[4];
#pragma unroll
      for (int mi = 0; mi < 4; ++mi)
        af[mi] = *reinterpret_cast<const short8*>(&As[wm * 64 + mi * 16 + lr][kh * 32 + lkb]);
#pragma unroll
      for (int ni = 0; ni < 4; ++ni)
        bfr[ni] = *reinterpret_cast<const short8*>(&Bs[wn * 64 + ni * 16 + lr][kh * 32 + lkb]);
#pragma unroll
      for (int mi = 0; mi < 4; ++mi)
#pragma unroll
        for (int ni = 0; ni < 4; ++ni)
          acc[mi][ni] = __builtin_amdgcn_mfma_f32_16x16x32_bf16(
              af[mi], bfr[ni], acc[mi][ni], 0, 0, 0);
    }
    __syncthreads();
  }

  // ---- epilogue: + sum_e g[n,e]*b[e,o], write fp32 ----
  const int orow0 = bm * BM + wm * 64;
  const int ocol0 = bn * BN + wn * 64;
  const int rq = (lane >> 4) * 4;
  const int cc = lane & 15;

  float bcol[4][NE];
#pragma unroll
  for (int ni = 0; ni < 4; ++ni) {
    const int col = ocol0 + ni * 16 + cc;
#pragma unroll
    for (int e = 0; e < NE; ++e) bcol[ni][e] = bias[e * DOUT + col];
  }

#pragma unroll
  for (int mi = 0; mi < 4; ++mi) {
#pragma unroll
    for (int q = 0; q < 4; ++q) {
      const int row = orow0 + mi * 16 + rq + q;
      const float4 g0 = *reinterpret_cast<const float4*>(gates + (size_t)row * NE);
      const float4 g1 = *reinterpret_cast<const float4*>(gates + (size_t)row * NE + 4);
#pragma unroll
      for (int ni = 0; ni < 4; ++ni) {
        float s = g0.x * bcol[ni][0] + g0.y * bcol[ni][1]
                + g0.z * bcol[ni][2] + g0.w * bcol[ni][3]
                + g1.x * bcol[ni][4] + g1.y * bcol[ni][5]
                + g1.z * bcol[ni][6] + g1.w * bcol[ni][7];
        out[(size_t)row * DOUT + ocol0 + ni * 16 + cc] = acc[mi][ni][q] + s;
      }
    }
  }
}

extern "C" void kernel_launch(void* const* d_in, const int* in_sizes, int n_in,
                              void* d_out, int out_size, void* d_ws, size_t ws_size,
                              hipStream_t stream) {
  const float* x  = (const float*)d_in[0];
  const float* ew = (const float*)d_in[1];
  const float* eb = (const float*)d_in[2];
  const float* gw = (const float*)d_in[3];
  const float* gb = (const float*)d_in[4];
  float* out = (float*)d_out;
  float* gates = (float*)d_ws;  // 8192*8 fp32 = 256 KB scratch

  gates_kernel<<<N_TOK / 4, 256, 0, stream>>>(x, gw, gb, gates);

  dim3 grid(N_TOK / BM, DOUT / BN);  // 64 x 8 = 512 blocks
  moe_gemm<<<grid, 256, 0, stream>>>(x, ew, eb, gates, out);
}